// Round 3
// baseline (203.718 us; speedup 1.0000x reference)
//
#include <hip/hip_runtime.h>
#include <hip/hip_cooperative_groups.h>

namespace cg = cooperative_groups;

#define N_SAMP 16384
#define N_CENT 4096
#define DIM    128
#define LAMBD  1.0f
#define NSLOT  256

typedef _Float16 half4v __attribute__((ext_vector_type(4)));
typedef _Float16 half8  __attribute__((ext_vector_type(8)));
typedef float    floatx4 __attribute__((ext_vector_type(4)));

// Single reduction line for the fused path.
struct Red { float sum; unsigned int cnt; unsigned int tkt; unsigned int pad[29]; };
// Per-block slots for the non-cooperative fallback path.
struct Slot { float sum; unsigned int cnt; unsigned int pad[30]; };

__device__ __forceinline__ void gload_lds16(const void* g, void* l) {
  __builtin_amdgcn_global_load_lds(
      (__attribute__((address_space(1))) void*)(g),
      (__attribute__((address_space(3))) void*)(l), 16, 0, 0);
}

// ---------------------------------------------------------------------------
// Fused single-launch kernel (cooperative, 256 blocks x 512 threads,
// 1 block/CU -- LDS 96 KB caps occupancy at 1, grid == CU count).
//
// Phase A (prep): each block converts its XCD-local E slice (64 rows:
//   Eh = (half)(2e), rowk = LAMBD + sum c_y(c_y-2e) in f32) and 16 C rows
//   (Ch = (half)c, c2 = ||c||^2 in f32). E-row partition matches phase B's
//   bm_grp = (bid&7)*2 + ((bid>>3)&1) mapping, so Eh/rowk lines are produced
//   and consumed on the same XCD L2. Block 0 zeroes the Red line.
//   __threadfence + grid.sync() publishes everything device-wide.
//
// Phase B (GEMM+mining): identical to round-2 kernel. acc is initialized to
//   rk[row]-c2[col] so post-MFMA acc IS the margin v; Eh pre-scaled by 2;
//   self pairs (v ~= LAMBD > 0) included and corrected exactly at the end
//   (cnt -= N_SAMP, sum -= N_SAMP*LAMBD). Count via ballot/popc (SALU).
//   Finalize: per-block atomics to one Red line + last-arriver ticket.
// ---------------------------------------------------------------------------
__global__ __launch_bounds__(512, 2) void fused_kernel(
    const float* __restrict__ E, const float* __restrict__ Cc,
    const int* __restrict__ tgt,
    _Float16* __restrict__ Eh, _Float16* __restrict__ Ch,
    float* __restrict__ c2, float* __restrict__ rowk,
    Red* __restrict__ red, float* __restrict__ out) {
  __shared__ _Float16 As[2][128 * DIM];   // 2 x 32 KB (double-buffered A)
  __shared__ _Float16 Bs[256 * DIM];      // 64 KB (B panel, staged once)
  __shared__ float swsum[8];
  __shared__ unsigned int swcnt[8];

  const int tid  = threadIdx.x;
  const int bid  = blockIdx.x;
  const int w    = tid >> 6;
  const int lane = tid & 63;

  // ---------------- Phase A: prep ----------------
  {
    const int h = tid >> 5;        // 0..15 half-wave id
    const int l = tid & 31;
    if (bid == 0 && tid == 0) { red->sum = 0.f; red->cnt = 0u; red->tkt = 0u; }
    // E rows: XCD-local 64-row chunk.
    const int erow0 = (bid & 7) * 2048 + (bid >> 3) * 64;
    #pragma unroll
    for (int it = 0; it < 4; ++it) {
      const int row = erow0 + it * 16 + h;
      float4 e = *(const float4*)(E + (size_t)row * DIM + l * 4);
      const int yi = tgt[row];
      float4 c = *(const float4*)(Cc + (size_t)yi * DIM + l * 4);
      float s = c.x * (c.x - 2.f * e.x) + c.y * (c.y - 2.f * e.y)
              + c.z * (c.z - 2.f * e.z) + c.w * (c.w - 2.f * e.w);
      #pragma unroll
      for (int off = 16; off > 0; off >>= 1) s += __shfl_xor(s, off);
      if (l == 0) rowk[row] = LAMBD + s;
      half4v hv;
      hv[0] = (_Float16)(2.f * e.x); hv[1] = (_Float16)(2.f * e.y);
      hv[2] = (_Float16)(2.f * e.z); hv[3] = (_Float16)(2.f * e.w);
      *(half4v*)(Eh + (size_t)row * DIM + l * 4) = hv;
    }
    // C rows: 16 per block.
    {
      const int row = bid * 16 + h;
      float4 c = *(const float4*)(Cc + (size_t)row * DIM + l * 4);
      float s = c.x * c.x + c.y * c.y + c.z * c.z + c.w * c.w;
      #pragma unroll
      for (int off = 16; off > 0; off >>= 1) s += __shfl_xor(s, off);
      if (l == 0) c2[row] = s;
      half4v hv;
      hv[0] = (_Float16)c.x; hv[1] = (_Float16)c.y;
      hv[2] = (_Float16)c.z; hv[3] = (_Float16)c.w;
      *(half4v*)(Ch + (size_t)row * DIM + l * 4) = hv;
    }
  }
  __threadfence();            // device-scope release of phase-A writes
  cg::this_grid().sync();     // execution + memory barrier across the grid
  __threadfence();            // acquire-side belt and braces

  // ---------------- Phase B: GEMM + mining ----------------
  const int xcd    = bid & 7;
  const int j      = bid >> 3;            // 0..31 within XCD
  const int bm_grp = xcd * 2 + (j & 1);   // 0..15, 8 A-tiles each
  const int bn_grp = j >> 1;              // 0..15
  const int bn0    = bn_grp * 256;

  const int p  = lane & 15;
  const int r4 = lane >> 4;

  // Stage B panel (64 KB) + A tile 0 (32 KB).
  {
    const char* gB = (const char*)(Ch + (size_t)bn0 * DIM);
    char* lB = (char*)Bs;
    #pragma unroll
    for (int it = 0; it < 8; ++it) {
      const int chunk = w * 8 + it;
      const int row   = chunk * 4 + r4;
      gload_lds16(gB + row * 256 + (p ^ (row & 15)) * 16, lB + chunk * 1024);
    }
    const char* gA = (const char*)(Eh + (size_t)bm_grp * 8 * 128 * DIM);
    char* lA = (char*)As[0];
    #pragma unroll
    for (int it = 0; it < 4; ++it) {
      const int chunk = w * 4 + it;
      const int row   = chunk * 4 + r4;
      gload_lds16(gA + row * 256 + (p ^ (row & 15)) * 16, lA + chunk * 1024);
    }
  }

  const int wm = w >> 2, wn = w & 3;      // 2 x 4 wave grid
  const int q = lane >> 4, r = lane & 15;
  const int row0 = wm * 64, col0 = wn * 64;

  float c2v[4];
  #pragma unroll
  for (int nt = 0; nt < 4; ++nt) c2v[nt] = c2[bn0 + col0 + nt * 16 + r];

  const float* rkbase = rowk + bm_grp * 8 * 128;
  floatx4 rkc[4], rkn[4];
  #pragma unroll
  for (int mt = 0; mt < 4; ++mt)
    rkc[mt] = *(const floatx4*)(rkbase + row0 + mt * 16 + q * 4);

  __syncthreads();   // B + A0 staged

  // Hoist B fragments to registers (reused across all 8 tiles).
  half8 bf[4][4];
  #pragma unroll
  for (int nt = 0; nt < 4; ++nt)
    #pragma unroll
    for (int ks = 0; ks < 4; ++ks)
      bf[nt][ks] = *(const half8*)&Bs[(col0 + nt * 16 + r) * DIM + (((ks * 4 + q) ^ r) * 8)];

  float lsum = 0.f;
  unsigned int cntU = 0u;

  for (int t = 0; t < 8; ++t) {
    const int cur = t & 1;

    if (t < 7) {
      const char* gA = (const char*)(Eh + (size_t)(bm_grp * 8 + t + 1) * 128 * DIM);
      char* lA = (char*)As[cur ^ 1];
      #pragma unroll
      for (int it = 0; it < 4; ++it) {
        const int chunk = w * 4 + it;
        const int row   = chunk * 4 + r4;
        gload_lds16(gA + row * 256 + (p ^ (row & 15)) * 16, lA + chunk * 1024);
      }
      #pragma unroll
      for (int mt = 0; mt < 4; ++mt)
        rkn[mt] = *(const floatx4*)(rkbase + (t + 1) * 128 + row0 + mt * 16 + q * 4);
    }

    floatx4 acc[4][4];
    #pragma unroll
    for (int mt = 0; mt < 4; ++mt)
      #pragma unroll
      for (int nt = 0; nt < 4; ++nt)
        acc[mt][nt] = rkc[mt] - c2v[nt];

    #pragma unroll
    for (int ks = 0; ks < 4; ++ks) {
      const int cidx = ks * 4 + q;
      half8 af[4];
      #pragma unroll
      for (int mt = 0; mt < 4; ++mt)
        af[mt] = *(const half8*)&As[cur][(row0 + mt * 16 + r) * DIM + ((cidx ^ r) * 8)];
      #pragma unroll
      for (int mt = 0; mt < 4; ++mt)
        #pragma unroll
        for (int nt = 0; nt < 4; ++nt)
          acc[mt][nt] = __builtin_amdgcn_mfma_f32_16x16x32_f16(af[mt], bf[nt][ks], acc[mt][nt], 0, 0, 0);
    }

    #pragma unroll
    for (int mt = 0; mt < 4; ++mt)
      #pragma unroll
      for (int nt = 0; nt < 4; ++nt) {
        const floatx4 a = acc[mt][nt];
        #pragma unroll
        for (int rg = 0; rg < 4; ++rg) {
          const float v = a[rg];
          lsum += fmaxf(v, 0.f);
          cntU += (unsigned int)__popcll(__ballot(v > 0.f));
        }
      }

    __syncthreads();
    #pragma unroll
    for (int mt = 0; mt < 4; ++mt) rkc[mt] = rkn[mt];
  }

  #pragma unroll
  for (int off = 32; off > 0; off >>= 1) lsum += __shfl_down(lsum, off);
  if (lane == 0) { swsum[w] = lsum; swcnt[w] = cntU; }
  __syncthreads();
  if (tid == 0) {
    float s = 0.f; unsigned int c = 0u;
    #pragma unroll
    for (int k = 0; k < 8; ++k) { s += swsum[k]; c += swcnt[k]; }
    atomicAdd(&red->sum, s);
    atomicAdd(&red->cnt, c);
    __threadfence();
    const unsigned int t = atomicAdd(&red->tkt, 1u);
    if (t == NSLOT - 1) {              // last arriver: fold + write out
      __threadfence();
      const float S = atomicAdd(&red->sum, 0.f);
      const unsigned int C = atomicAdd(&red->cnt, 0u);
      const float Sc = S - (float)N_SAMP * LAMBD;
      const long long Cn = (long long)C - (long long)N_SAMP;
      out[0] = (Cn > 0) ? (Sc / (float)Cn) : 0.f;
    }
  }
}

// ---------------------------------------------------------------------------
// Non-cooperative fallback path (round-2 structure): prep + gemm kernels.
// ---------------------------------------------------------------------------
__global__ __launch_bounds__(256) void prep_kernel(
    const float* __restrict__ E, const float* __restrict__ Cc,
    const int* __restrict__ tgt,
    _Float16* __restrict__ Eh, _Float16* __restrict__ Ch,
    float* __restrict__ c2, float* __restrict__ rowk,
    Slot* __restrict__ slots) {
  const int tid  = threadIdx.x;
  const int w    = tid >> 6;
  const int lane = tid & 63;
  const int l    = lane & 31;
  const int E_BLOCKS = N_SAMP / 8;   // 2048

  if ((int)blockIdx.x < E_BLOCKS) {
    if (blockIdx.x == 0) {
      slots[tid].sum = 0.f; slots[tid].cnt = 0u; slots[tid].pad[0] = 0u;
    }
    const int wv = blockIdx.x * 4 + w;
    const int r0 = wv * 2 + (lane >> 5);
    float4 e = *(const float4*)(E + (size_t)r0 * DIM + l * 4);
    const int yi = tgt[r0];
    float4 c = *(const float4*)(Cc + (size_t)yi * DIM + l * 4);
    float s = c.x * (c.x - 2.f * e.x) + c.y * (c.y - 2.f * e.y)
            + c.z * (c.z - 2.f * e.z) + c.w * (c.w - 2.f * e.w);
    #pragma unroll
    for (int off = 16; off > 0; off >>= 1) s += __shfl_xor(s, off);
    if (l == 0) rowk[r0] = LAMBD + s;
    half4v h;
    h[0] = (_Float16)(2.f * e.x); h[1] = (_Float16)(2.f * e.y);
    h[2] = (_Float16)(2.f * e.z); h[3] = (_Float16)(2.f * e.w);
    *(half4v*)(Eh + (size_t)r0 * DIM + l * 4) = h;
  } else {
    const int wv = ((int)blockIdx.x - E_BLOCKS) * 4 + w;
    const int r0 = wv * 2 + (lane >> 5);
    float4 c = *(const float4*)(Cc + (size_t)r0 * DIM + l * 4);
    float s = c.x * c.x + c.y * c.y + c.z * c.z + c.w * c.w;
    #pragma unroll
    for (int off = 16; off > 0; off >>= 1) s += __shfl_xor(s, off);
    if (l == 0) c2[r0] = s;
    half4v h;
    h[0] = (_Float16)c.x; h[1] = (_Float16)c.y;
    h[2] = (_Float16)c.z; h[3] = (_Float16)c.w;
    *(half4v*)(Ch + (size_t)r0 * DIM + l * 4) = h;
  }
}

__global__ __launch_bounds__(512, 2) void center_gemm_kernel(
    const _Float16* __restrict__ Eh, const _Float16* __restrict__ Ch,
    const float* __restrict__ c2, const float* __restrict__ rowk,
    Slot* __restrict__ slots, float* __restrict__ out) {
  __shared__ _Float16 As[2][128 * DIM];
  __shared__ _Float16 Bs[256 * DIM];
  __shared__ float swsum[8];
  __shared__ unsigned int swcnt[8];
  __shared__ int tktS;

  const int tid  = threadIdx.x;
  const int w    = tid >> 6;
  const int lane = tid & 63;

  const int bid    = blockIdx.x;
  const int xcd    = bid & 7;
  const int j      = bid >> 3;
  const int bm_grp = xcd * 2 + (j & 1);
  const int bn_grp = j >> 1;
  const int bn0    = bn_grp * 256;

  const int p  = lane & 15;
  const int r4 = lane >> 4;

  {
    const char* gB = (const char*)(Ch + (size_t)bn0 * DIM);
    char* lB = (char*)Bs;
    #pragma unroll
    for (int it = 0; it < 8; ++it) {
      const int chunk = w * 8 + it;
      const int row   = chunk * 4 + r4;
      gload_lds16(gB + row * 256 + (p ^ (row & 15)) * 16, lB + chunk * 1024);
    }
    const char* gA = (const char*)(Eh + (size_t)bm_grp * 8 * 128 * DIM);
    char* lA = (char*)As[0];
    #pragma unroll
    for (int it = 0; it < 4; ++it) {
      const int chunk = w * 4 + it;
      const int row   = chunk * 4 + r4;
      gload_lds16(gA + row * 256 + (p ^ (row & 15)) * 16, lA + chunk * 1024);
    }
  }

  const int wm = w >> 2, wn = w & 3;
  const int q = lane >> 4, r = lane & 15;
  const int row0 = wm * 64, col0 = wn * 64;

  float c2v[4];
  #pragma unroll
  for (int nt = 0; nt < 4; ++nt) c2v[nt] = c2[bn0 + col0 + nt * 16 + r];

  const float* rkbase = rowk + bm_grp * 8 * 128;
  floatx4 rkc[4], rkn[4];
  #pragma unroll
  for (int mt = 0; mt < 4; ++mt)
    rkc[mt] = *(const floatx4*)(rkbase + row0 + mt * 16 + q * 4);

  __syncthreads();

  half8 bf[4][4];
  #pragma unroll
  for (int nt = 0; nt < 4; ++nt)
    #pragma unroll
    for (int ks = 0; ks < 4; ++ks)
      bf[nt][ks] = *(const half8*)&Bs[(col0 + nt * 16 + r) * DIM + (((ks * 4 + q) ^ r) * 8)];

  float lsum = 0.f;
  unsigned int cntU = 0u;

  for (int t = 0; t < 8; ++t) {
    const int cur = t & 1;
    if (t < 7) {
      const char* gA = (const char*)(Eh + (size_t)(bm_grp * 8 + t + 1) * 128 * DIM);
      char* lA = (char*)As[cur ^ 1];
      #pragma unroll
      for (int it = 0; it < 4; ++it) {
        const int chunk = w * 4 + it;
        const int row   = chunk * 4 + r4;
        gload_lds16(gA + row * 256 + (p ^ (row & 15)) * 16, lA + chunk * 1024);
      }
      #pragma unroll
      for (int mt = 0; mt < 4; ++mt)
        rkn[mt] = *(const floatx4*)(rkbase + (t + 1) * 128 + row0 + mt * 16 + q * 4);
    }

    floatx4 acc[4][4];
    #pragma unroll
    for (int mt = 0; mt < 4; ++mt)
      #pragma unroll
      for (int nt = 0; nt < 4; ++nt)
        acc[mt][nt] = rkc[mt] - c2v[nt];

    #pragma unroll
    for (int ks = 0; ks < 4; ++ks) {
      const int cidx = ks * 4 + q;
      half8 af[4];
      #pragma unroll
      for (int mt = 0; mt < 4; ++mt)
        af[mt] = *(const half8*)&As[cur][(row0 + mt * 16 + r) * DIM + ((cidx ^ r) * 8)];
      #pragma unroll
      for (int mt = 0; mt < 4; ++mt)
        #pragma unroll
        for (int nt = 0; nt < 4; ++nt)
          acc[mt][nt] = __builtin_amdgcn_mfma_f32_16x16x32_f16(af[mt], bf[nt][ks], acc[mt][nt], 0, 0, 0);
    }

    #pragma unroll
    for (int mt = 0; mt < 4; ++mt)
      #pragma unroll
      for (int nt = 0; nt < 4; ++nt) {
        const floatx4 a = acc[mt][nt];
        #pragma unroll
        for (int rg = 0; rg < 4; ++rg) {
          const float v = a[rg];
          lsum += fmaxf(v, 0.f);
          cntU += (unsigned int)__popcll(__ballot(v > 0.f));
        }
      }

    __syncthreads();
    #pragma unroll
    for (int mt = 0; mt < 4; ++mt) rkc[mt] = rkn[mt];
  }

  #pragma unroll
  for (int off = 32; off > 0; off >>= 1) lsum += __shfl_down(lsum, off);
  if (lane == 0) { swsum[w] = lsum; swcnt[w] = cntU; }
  __syncthreads();
  if (tid == 0) {
    float s = 0.f; unsigned int c = 0u;
    #pragma unroll
    for (int k = 0; k < 8; ++k) { s += swsum[k]; c += swcnt[k]; }
    Slot* sl = &slots[bid];
    atomicAdd(&sl->sum, s);
    atomicAdd(&sl->cnt, c);
    __threadfence();
    tktS = (int)atomicAdd(&slots[0].pad[0], 1u);
  }
  __syncthreads();

  if (tktS == NSLOT - 1) {
    float s = 0.f; unsigned int c = 0u;
    if (tid < NSLOT) {
      s = atomicAdd(&slots[tid].sum, 0.f);
      c = atomicAdd(&slots[tid].cnt, 0u);
    }
    #pragma unroll
    for (int off = 32; off > 0; off >>= 1) {
      s += __shfl_down(s, off);
      c += __shfl_down(c, off);
    }
    if (lane == 0) { swsum[w] = s; swcnt[w] = c; }
    __syncthreads();
    if (tid == 0) {
      float S = 0.f; unsigned int C = 0u;
      #pragma unroll
      for (int k = 0; k < 8; ++k) { S += swsum[k]; C += swcnt[k]; }
      const float Sc = S - (float)N_SAMP * LAMBD;
      const long long Cn = (long long)C - (long long)N_SAMP;
      out[0] = (Cn > 0) ? (Sc / (float)Cn) : 0.f;
    }
  }
}

// ---------------------------------------------------------------------------
// Fallback (tiny ws): fp32 vector path, one block per sample. Exact.
// ---------------------------------------------------------------------------
__global__ void zero_kernel(float* ws_sum, unsigned int* ws_cnt) {
  if (threadIdx.x == 0) { *ws_sum = 0.f; *ws_cnt = 0u; }
}

__global__ void finalize_simple(const float* __restrict__ ws_sum,
                                const unsigned int* __restrict__ ws_cnt,
                                float* __restrict__ out) {
  if (threadIdx.x == 0 && blockIdx.x == 0) {
    const unsigned int c = *ws_cnt;
    out[0] = (c > 0u) ? (*ws_sum / (float)c) : 0.f;
  }
}

__global__ __launch_bounds__(256) void fallback_kernel(
    const float* __restrict__ E, const float* __restrict__ Cc,
    const int* __restrict__ tgt,
    float* __restrict__ ws_sum, unsigned int* __restrict__ ws_cnt) {
  __shared__ float eS[DIM];
  __shared__ float apS;
  const int i = blockIdx.x;
  const int tid = threadIdx.x;
  if (tid < DIM) eS[tid] = E[(size_t)i * DIM + tid];
  __syncthreads();
  const int yi = tgt[i];
  float dloc[16];
  #pragma unroll
  for (int j = 0; j < 16; ++j) {
    const int c = tid + 256 * j;
    const float* cp = Cc + (size_t)c * DIM;
    float s = 0.f;
    for (int d = 0; d < DIM; d += 4) {
      float4 cv = *(const float4*)(cp + d);
      s += cv.x * (cv.x - 2.f * eS[d + 0]) + cv.y * (cv.y - 2.f * eS[d + 1])
         + cv.z * (cv.z - 2.f * eS[d + 2]) + cv.w * (cv.w - 2.f * eS[d + 3]);
    }
    dloc[j] = s;
    if (c == yi) apS = s;
  }
  __syncthreads();
  const float apv = apS;
  float lsum = 0.f; int lcnt = 0;
  #pragma unroll
  for (int j = 0; j < 16; ++j) {
    const int c = tid + 256 * j;
    const float v = LAMBD + apv - dloc[j];
    const bool mined = (v > 0.f) & (c != yi);
    lsum += mined ? v : 0.f;
    lcnt += mined ? 1 : 0;
  }
  #pragma unroll
  for (int off = 32; off > 0; off >>= 1) {
    lsum += __shfl_down(lsum, off);
    lcnt += __shfl_down(lcnt, off);
  }
  __shared__ float swsum[4];
  __shared__ int   swcnt[4];
  const int w = tid >> 6, lane = tid & 63;
  if (lane == 0) { swsum[w] = lsum; swcnt[w] = lcnt; }
  __syncthreads();
  if (tid == 0) {
    atomicAdd(ws_sum, swsum[0] + swsum[1] + swsum[2] + swsum[3]);
    atomicAdd(ws_cnt, (unsigned int)(swcnt[0] + swcnt[1] + swcnt[2] + swcnt[3]));
  }
}

extern "C" void kernel_launch(void* const* d_in, const int* in_sizes, int n_in,
                              void* d_out, int out_size, void* d_ws, size_t ws_size,
                              hipStream_t stream) {
  const float* E   = (const float*)d_in[0];
  const int*   tgt = (const int*)d_in[1];
  const float* Cc  = (const float*)d_in[2];
  float* out = (float*)d_out;

  const size_t EH_BYTES = (size_t)N_SAMP * DIM * 2;     // 4 MB
  const size_t CH_BYTES = (size_t)N_CENT * DIM * 2;     // 1 MB
  const size_t C2_BYTES = (size_t)N_CENT * 4;           // 16 KB
  const size_t RK_BYTES = (size_t)N_SAMP * 4;           // 64 KB
  const size_t SL_BYTES = (size_t)NSLOT * sizeof(Slot); // 32 KB
  const size_t NEEDED = EH_BYTES + CH_BYTES + C2_BYTES + RK_BYTES + SL_BYTES;

  static int coop_ok = -1;
  if (coop_ok < 0) {
    int dev = 0, v = 0;
    hipGetDevice(&dev);
    hipDeviceGetAttribute(&v, hipDeviceAttributeCooperativeLaunch, dev);
    coop_ok = v;
  }

  char* ws = (char*)d_ws;
  if (ws_size >= NEEDED) {
    _Float16* Eh = (_Float16*)ws;
    _Float16* Ch = (_Float16*)(ws + EH_BYTES);
    float* c2    = (float*)(ws + EH_BYTES + CH_BYTES);
    float* rowk  = (float*)(ws + EH_BYTES + CH_BYTES + C2_BYTES);
    char* slbase = ws + EH_BYTES + CH_BYTES + C2_BYTES + RK_BYTES;

    if (coop_ok) {
      Red* red = (Red*)slbase;
      void* args[] = {(void*)&E, (void*)&Cc, (void*)&tgt, (void*)&Eh,
                      (void*)&Ch, (void*)&c2, (void*)&rowk, (void*)&red,
                      (void*)&out};
      hipError_t err = hipLaunchCooperativeKernel(
          (const void*)fused_kernel, dim3(256), dim3(512), args, 0, stream);
      if (err == hipSuccess) return;
      coop_ok = 0;  // fall through to the 2-kernel path
    }
    Slot* slots = (Slot*)slbase;
    const int E_BLOCKS = N_SAMP / 8;   // 2048
    const int C_BLOCKS = N_CENT / 8;   // 512
    prep_kernel<<<E_BLOCKS + C_BLOCKS, 256, 0, stream>>>(
        E, Cc, tgt, Eh, Ch, c2, rowk, slots);
    center_gemm_kernel<<<256, 512, 0, stream>>>(Eh, Ch, c2, rowk, slots, out);
  } else {
    float* ws_sum = (float*)ws;
    unsigned int* ws_cnt = (unsigned int*)(ws_sum + 1);
    zero_kernel<<<1, 64, 0, stream>>>(ws_sum, ws_cnt);
    fallback_kernel<<<N_SAMP, 256, 0, stream>>>(E, Cc, tgt, ws_sum, ws_cnt);
    finalize_simple<<<1, 64, 0, stream>>>(ws_sum, ws_cnt, out);
  }
}

// Round 4
// 92.507 us; speedup vs baseline: 2.2022x; 2.2022x over previous
//
#include <hip/hip_runtime.h>

#define N_SAMP 16384
#define N_CENT 4096
#define DIM    128
#define LAMBD  1.0f
#define NSLOT  256

typedef _Float16 half4v __attribute__((ext_vector_type(4)));
typedef _Float16 half8  __attribute__((ext_vector_type(8)));
typedef float    floatx4 __attribute__((ext_vector_type(4)));

// One accumulation slot per 128-B cache line. Grid is exactly NSLOT blocks ->
// each block owns its own slot (zero contention, no cross-block traffic).
struct Slot { float sum; unsigned int cnt; unsigned int pad[30]; };

__device__ __forceinline__ void gload_lds16(const void* g, void* l) {
  __builtin_amdgcn_global_load_lds(
      (__attribute__((address_space(1))) void*)(g),
      (__attribute__((address_space(3))) void*)(l), 16, 0, 0);
}

// ---------------------------------------------------------------------------
// Fused prep (single launch, 2560 blocks):
//   blocks [0, 2048): E rows. One wave handles 2 rows (half-wave per row,
//     float4/lane): computes rowk[i] = LAMBD + sum c*(c-2e) over center y_i
//     (f32) AND converts/stores Eh = (half)(2e) from the same load. The 2x
//     scale is exact in f16, so the GEMM's 2*e.c is just Eh.c.
//     Block 0 additionally zeroes the accumulation slots.
//   blocks [2048, 2560): C rows. One wave = 2 rows: c2[c] = ||c||^2 (f32)
//     AND Ch = (half)c from the same load.
// E is read ONCE, C once.
// ---------------------------------------------------------------------------
__global__ __launch_bounds__(256) void prep_kernel(
    const float* __restrict__ E, const float* __restrict__ Cc,
    const int* __restrict__ tgt,
    _Float16* __restrict__ Eh, _Float16* __restrict__ Ch,
    float* __restrict__ c2, float* __restrict__ rowk,
    Slot* __restrict__ slots) {
  const int tid  = threadIdx.x;
  const int w    = tid >> 6;
  const int lane = tid & 63;
  const int l    = lane & 31;
  const int E_BLOCKS = N_SAMP / 8;   // 2048 (4 waves x 2 rows per block)

  if ((int)blockIdx.x < E_BLOCKS) {
    if (blockIdx.x == 0) { slots[tid].sum = 0.f; slots[tid].cnt = 0u; }
    const int wv = blockIdx.x * 4 + w;           // 0..8191
    const int r0 = wv * 2 + (lane >> 5);         // row, per half-wave
    float4 e = *(const float4*)(E + (size_t)r0 * DIM + l * 4);
    const int yi = tgt[r0];
    float4 c = *(const float4*)(Cc + (size_t)yi * DIM + l * 4);
    float s = c.x * (c.x - 2.f * e.x) + c.y * (c.y - 2.f * e.y)
            + c.z * (c.z - 2.f * e.z) + c.w * (c.w - 2.f * e.w);
    #pragma unroll
    for (int off = 16; off > 0; off >>= 1) s += __shfl_xor(s, off);
    if (l == 0) rowk[r0] = LAMBD + s;
    half4v h;
    h[0] = (_Float16)(2.f * e.x); h[1] = (_Float16)(2.f * e.y);
    h[2] = (_Float16)(2.f * e.z); h[3] = (_Float16)(2.f * e.w);
    *(half4v*)(Eh + (size_t)r0 * DIM + l * 4) = h;
  } else {
    const int wv = ((int)blockIdx.x - E_BLOCKS) * 4 + w;  // 0..2047
    const int r0 = wv * 2 + (lane >> 5);                  // center row
    float4 c = *(const float4*)(Cc + (size_t)r0 * DIM + l * 4);
    float s = c.x * c.x + c.y * c.y + c.z * c.z + c.w * c.w;
    #pragma unroll
    for (int off = 16; off > 0; off >>= 1) s += __shfl_xor(s, off);
    if (l == 0) c2[r0] = s;
    half4v h;
    h[0] = (_Float16)c.x; h[1] = (_Float16)c.y;
    h[2] = (_Float16)c.z; h[3] = (_Float16)c.w;
    *(half4v*)(Ch + (size_t)r0 * DIM + l * 4) = h;
  }
}

// ---------------------------------------------------------------------------
// GEMM + mining. 256 blocks x 512 threads, 1 block/CU (128 KB LDS).
//  - acc initialized to rk[row]-c2[col] (MFMA C-in), Eh pre-scaled by 2 ->
//    after the K-chain acc IS the margin value v directly.
//  - self pair (col == y_row) has v ~= LAMBD > 0 always, so it is NOT masked
//    in the hot loop; finalize subtracts exactly N_SAMP from cnt and
//    N_SAMP*LAMBD from sum.
//  - sum via fmax+add (VALU), count via ballot/popc (SALU pipe, wave-uniform).
//  - B panel staged to LDS once, fragments hoisted to registers; A tiles
//    double-buffered via global_load_lds; rowk register double-buffered.
//  - NO fused finalize: per-block atomic to its OWN slot line (no fence, no
//    ticket, no cross-XCD sweep) -- the serialized tail in round 2's fused
//    version is the suspected +1.6us regression. Finalize is a separate
//    1-block kernel.
// ---------------------------------------------------------------------------
__global__ __launch_bounds__(512, 2) void center_gemm_kernel(
    const _Float16* __restrict__ Eh, const _Float16* __restrict__ Ch,
    const float* __restrict__ c2, const float* __restrict__ rowk,
    Slot* __restrict__ slots) {
  __shared__ _Float16 As[2][128 * DIM];   // 2 x 32 KB (double-buffered A)
  __shared__ _Float16 Bs[256 * DIM];      // 64 KB (B panel, staged once)
  __shared__ float swsum[8];
  __shared__ unsigned int swcnt[8];

  const int tid  = threadIdx.x;
  const int w    = tid >> 6;
  const int lane = tid & 63;

  const int bid    = blockIdx.x;
  const int xcd    = bid & 7;
  const int j      = bid >> 3;            // 0..31 within XCD
  const int bm_grp = xcd * 2 + (j & 1);   // 0..15, 8 A-tiles each
  const int bn_grp = j >> 1;              // 0..15
  const int bn0    = bn_grp * 256;

  const int p  = lane & 15;
  const int r4 = lane >> 4;

  // ---- prologue: stage B panel (64 KB) + A tile 0 (32 KB)
  {
    const char* gB = (const char*)(Ch + (size_t)bn0 * DIM);
    char* lB = (char*)Bs;
    #pragma unroll
    for (int it = 0; it < 8; ++it) {
      const int chunk = w * 8 + it;             // 64 x 1 KB chunks
      const int row   = chunk * 4 + r4;
      gload_lds16(gB + row * 256 + (p ^ (row & 15)) * 16, lB + chunk * 1024);
    }
    const char* gA = (const char*)(Eh + (size_t)bm_grp * 8 * 128 * DIM);
    char* lA = (char*)As[0];
    #pragma unroll
    for (int it = 0; it < 4; ++it) {
      const int chunk = w * 4 + it;             // 32 x 1 KB chunks
      const int row   = chunk * 4 + r4;
      gload_lds16(gA + row * 256 + (p ^ (row & 15)) * 16, lA + chunk * 1024);
    }
  }

  const int wm = w >> 2, wn = w & 3;            // 2 x 4 wave grid
  const int q = lane >> 4, r = lane & 15;
  const int row0 = wm * 64, col0 = wn * 64;

  // c2 for this wave's 4 col-groups (loop-invariant), L2-hot.
  float c2v[4];
  #pragma unroll
  for (int nt = 0; nt < 4; ++nt) c2v[nt] = c2[bn0 + col0 + nt * 16 + r];

  // rowk for tile 0, register double-buffer (16B-aligned float4 loads).
  const float* rkbase = rowk + bm_grp * 8 * 128;
  floatx4 rkc[4], rkn[4];
  #pragma unroll
  for (int mt = 0; mt < 4; ++mt)
    rkc[mt] = *(const floatx4*)(rkbase + row0 + mt * 16 + q * 4);

  __syncthreads();   // B + A0 staged

  // Hoist all B fragments to registers (reused across all 8 tiles).
  half8 bf[4][4];
  #pragma unroll
  for (int nt = 0; nt < 4; ++nt)
    #pragma unroll
    for (int ks = 0; ks < 4; ++ks)
      bf[nt][ks] = *(const half8*)&Bs[(col0 + nt * 16 + r) * DIM + (((ks * 4 + q) ^ r) * 8)];

  float lsum = 0.f;
  unsigned int cntU = 0u;   // wave-uniform (ballot/popc)

  for (int t = 0; t < 8; ++t) {
    const int cur = t & 1;

    // Prefetch A tile t+1 (async to LDS) + its rowk slice (to regs).
    if (t < 7) {
      const char* gA = (const char*)(Eh + (size_t)(bm_grp * 8 + t + 1) * 128 * DIM);
      char* lA = (char*)As[cur ^ 1];
      #pragma unroll
      for (int it = 0; it < 4; ++it) {
        const int chunk = w * 4 + it;
        const int row   = chunk * 4 + r4;
        gload_lds16(gA + row * 256 + (p ^ (row & 15)) * 16, lA + chunk * 1024);
      }
      #pragma unroll
      for (int mt = 0; mt < 4; ++mt)
        rkn[mt] = *(const floatx4*)(rkbase + (t + 1) * 128 + row0 + mt * 16 + q * 4);
    }

    // acc := rk[row] - c2[col]; after the K-chain acc == v directly.
    floatx4 acc[4][4];
    #pragma unroll
    for (int mt = 0; mt < 4; ++mt)
      #pragma unroll
      for (int nt = 0; nt < 4; ++nt)
        acc[mt][nt] = rkc[mt] - c2v[nt];

    #pragma unroll
    for (int ks = 0; ks < 4; ++ks) {
      const int cidx = ks * 4 + q;
      half8 af[4];
      #pragma unroll
      for (int mt = 0; mt < 4; ++mt)
        af[mt] = *(const half8*)&As[cur][(row0 + mt * 16 + r) * DIM + ((cidx ^ r) * 8)];
      #pragma unroll
      for (int mt = 0; mt < 4; ++mt)
        #pragma unroll
        for (int nt = 0; nt < 4; ++nt)
          acc[mt][nt] = __builtin_amdgcn_mfma_f32_16x16x32_f16(af[mt], bf[nt][ks], acc[mt][nt], 0, 0, 0);
    }

    // Mining epilogue: sum on VALU, count on SALU.
    #pragma unroll
    for (int mt = 0; mt < 4; ++mt)
      #pragma unroll
      for (int nt = 0; nt < 4; ++nt) {
        const floatx4 a = acc[mt][nt];
        #pragma unroll
        for (int rg = 0; rg < 4; ++rg) {
          const float v = a[rg];
          lsum += fmaxf(v, 0.f);
          cntU += (unsigned int)__popcll(__ballot(v > 0.f));
        }
      }

    __syncthreads();   // drains A(t+1) prefetch; protects As[cur] for t+2
    #pragma unroll
    for (int mt = 0; mt < 4; ++mt) rkc[mt] = rkn[mt];
  }

  // Block reduction: lsum per-lane, cntU wave-uniform.
  #pragma unroll
  for (int off = 32; off > 0; off >>= 1) lsum += __shfl_down(lsum, off);
  if (lane == 0) { swsum[w] = lsum; swcnt[w] = cntU; }
  __syncthreads();
  if (tid == 0) {
    float s = 0.f; unsigned int c = 0u;
    #pragma unroll
    for (int k = 0; k < 8; ++k) { s += swsum[k]; c += swcnt[k]; }
    Slot* sl = &slots[bid];
    atomicAdd(&sl->sum, s);
    atomicAdd(&sl->cnt, c);
  }
}

__global__ __launch_bounds__(256) void finalize_kernel(
    const Slot* __restrict__ slots, float* __restrict__ out) {
  const int tid = threadIdx.x;
  float s = slots[tid].sum;
  unsigned int c = slots[tid].cnt;
  #pragma unroll
  for (int off = 32; off > 0; off >>= 1) {
    s += __shfl_down(s, off);
    c += __shfl_down(c, off);
  }
  __shared__ float ss[4];
  __shared__ unsigned int sc[4];
  if ((tid & 63) == 0) { ss[tid >> 6] = s; sc[tid >> 6] = c; }
  __syncthreads();
  if (tid == 0) {
    const float S = ss[0] + ss[1] + ss[2] + ss[3];
    const unsigned int C = sc[0] + sc[1] + sc[2] + sc[3];
    // Exact self correction: every self pair has v = LAMBD + O(f16 eps) > 0,
    // so exactly N_SAMP self hits were counted; each contributed ~LAMBD.
    const float Sc = S - (float)N_SAMP * LAMBD;
    const long long Cn = (long long)C - (long long)N_SAMP;
    out[0] = (Cn > 0) ? (Sc / (float)Cn) : 0.f;
  }
}

// ---------------------------------------------------------------------------
// Fallback (tiny ws): fp32 vector path, one block per sample. Exact.
// ---------------------------------------------------------------------------
__global__ void zero_kernel(float* ws_sum, unsigned int* ws_cnt) {
  if (threadIdx.x == 0) { *ws_sum = 0.f; *ws_cnt = 0u; }
}

__global__ void finalize_simple(const float* __restrict__ ws_sum,
                                const unsigned int* __restrict__ ws_cnt,
                                float* __restrict__ out) {
  if (threadIdx.x == 0 && blockIdx.x == 0) {
    const unsigned int c = *ws_cnt;
    out[0] = (c > 0u) ? (*ws_sum / (float)c) : 0.f;
  }
}

__global__ __launch_bounds__(256) void fallback_kernel(
    const float* __restrict__ E, const float* __restrict__ Cc,
    const int* __restrict__ tgt,
    float* __restrict__ ws_sum, unsigned int* __restrict__ ws_cnt) {
  __shared__ float eS[DIM];
  __shared__ float apS;
  const int i = blockIdx.x;
  const int tid = threadIdx.x;
  if (tid < DIM) eS[tid] = E[(size_t)i * DIM + tid];
  __syncthreads();
  const int yi = tgt[i];
  float dloc[16];
  #pragma unroll
  for (int j = 0; j < 16; ++j) {
    const int c = tid + 256 * j;
    const float* cp = Cc + (size_t)c * DIM;
    float s = 0.f;
    for (int d = 0; d < DIM; d += 4) {
      float4 cv = *(const float4*)(cp + d);
      s += cv.x * (cv.x - 2.f * eS[d + 0]) + cv.y * (cv.y - 2.f * eS[d + 1])
         + cv.z * (cv.z - 2.f * eS[d + 2]) + cv.w * (cv.w - 2.f * eS[d + 3]);
    }
    dloc[j] = s;
    if (c == yi) apS = s;
  }
  __syncthreads();
  const float apv = apS;
  float lsum = 0.f; int lcnt = 0;
  #pragma unroll
  for (int j = 0; j < 16; ++j) {
    const int c = tid + 256 * j;
    const float v = LAMBD + apv - dloc[j];
    const bool mined = (v > 0.f) & (c != yi);
    lsum += mined ? v : 0.f;
    lcnt += mined ? 1 : 0;
  }
  #pragma unroll
  for (int off = 32; off > 0; off >>= 1) {
    lsum += __shfl_down(lsum, off);
    lcnt += __shfl_down(lcnt, off);
  }
  __shared__ float swsum[4];
  __shared__ int   swcnt[4];
  const int w = tid >> 6, lane = tid & 63;
  if (lane == 0) { swsum[w] = lsum; swcnt[w] = lcnt; }
  __syncthreads();
  if (tid == 0) {
    atomicAdd(ws_sum, swsum[0] + swsum[1] + swsum[2] + swsum[3]);
    atomicAdd(ws_cnt, (unsigned int)(swcnt[0] + swcnt[1] + swcnt[2] + swcnt[3]));
  }
}

extern "C" void kernel_launch(void* const* d_in, const int* in_sizes, int n_in,
                              void* d_out, int out_size, void* d_ws, size_t ws_size,
                              hipStream_t stream) {
  const float* E   = (const float*)d_in[0];
  const int*   tgt = (const int*)d_in[1];
  const float* Cc  = (const float*)d_in[2];
  float* out = (float*)d_out;

  const size_t EH_BYTES = (size_t)N_SAMP * DIM * 2;     // 4 MB
  const size_t CH_BYTES = (size_t)N_CENT * DIM * 2;     // 1 MB
  const size_t C2_BYTES = (size_t)N_CENT * 4;           // 16 KB
  const size_t RK_BYTES = (size_t)N_SAMP * 4;           // 64 KB
  const size_t SL_BYTES = (size_t)NSLOT * sizeof(Slot); // 32 KB
  const size_t NEEDED = EH_BYTES + CH_BYTES + C2_BYTES + RK_BYTES + SL_BYTES;

  char* ws = (char*)d_ws;
  if (ws_size >= NEEDED) {
    _Float16* Eh = (_Float16*)ws;
    _Float16* Ch = (_Float16*)(ws + EH_BYTES);
    float* c2    = (float*)(ws + EH_BYTES + CH_BYTES);
    float* rowk  = (float*)(ws + EH_BYTES + CH_BYTES + C2_BYTES);
    Slot* slots  = (Slot*)(ws + EH_BYTES + CH_BYTES + C2_BYTES + RK_BYTES);

    const int E_BLOCKS = N_SAMP / 8;   // 2048
    const int C_BLOCKS = N_CENT / 8;   // 512
    prep_kernel<<<E_BLOCKS + C_BLOCKS, 256, 0, stream>>>(
        E, Cc, tgt, Eh, Ch, c2, rowk, slots);
    center_gemm_kernel<<<256, 512, 0, stream>>>(Eh, Ch, c2, rowk, slots);
    finalize_kernel<<<1, 256, 0, stream>>>(slots, out);
  } else {
    float* ws_sum = (float*)ws;
    unsigned int* ws_cnt = (unsigned int*)(ws_sum + 1);
    zero_kernel<<<1, 64, 0, stream>>>(ws_sum, ws_cnt);
    fallback_kernel<<<N_SAMP, 256, 0, stream>>>(E, Cc, tgt, ws_sum, ws_cnt);
    finalize_simple<<<1, 64, 0, stream>>>(ws_sum, ws_cnt, out);
  }
}